// Round 12
// baseline (80.666 us; speedup 1.0000x reference)
//
#include <hip/hip_runtime.h>
#include <hip/hip_bf16.h>

#define TT 8192
#define DIN 512
#define DQK 64

typedef __attribute__((ext_vector_type(8))) short short8;
typedef __attribute__((ext_vector_type(4))) float f32x4;

static __device__ __forceinline__ short8 cvt8(const float* p) {
    short tmp[8];
    #pragma unroll
    for (int j = 0; j < 8; ++j) {
        __hip_bfloat16 h = __float2bfloat16(p[j]);
        tmp[j] = *(short*)&h;
    }
    return *(short8*)tmp;
}

// ---------------- Kernel 0: fused zero(d_out) + wconv (W -> WT bf16) ----------------
__global__ __launch_bounds__(256) void init_kernel(
    const float* __restrict__ Wq, const float* __restrict__ Wk, const float* __restrict__ Wv,
    __hip_bfloat16* __restrict__ wtb, float* __restrict__ out, int n4)
{
    __shared__ float tile[64][65];
    const int b = blockIdx.x;
    const int tid = threadIdx.x;

    if (b >= 24) {
        const int nthr = 24 * 256;
        for (int i = (b - 24) * 256 + tid; i < n4; i += nthr)
            ((f32x4*)out)[i] = (f32x4){0.f, 0.f, 0.f, 0.f};
        return;
    }

    const int m = b >> 3;
    const float* W = m == 0 ? Wq : (m == 1 ? Wk : Wv);
    const int k0 = (b & 7) * 64;

    {
        const int col4 = (tid & 15) * 4;
        #pragma unroll
        for (int it = 0; it < 4; ++it) {
            const int row = (tid >> 4) + it * 16;
            float4 v = *(const float4*)&W[(size_t)(k0 + row) * DQK + col4];
            tile[row][col4 + 0] = v.x; tile[row][col4 + 1] = v.y;
            tile[row][col4 + 2] = v.z; tile[row][col4 + 3] = v.w;
        }
    }
    __syncthreads();
    {
        const int d = tid >> 2;
        const int kc = (tid & 3) * 16;
        short tmp[16];
        #pragma unroll
        for (int j = 0; j < 16; ++j) {
            __hip_bfloat16 h = __float2bfloat16(tile[kc + j][d]);
            tmp[j] = *(short*)&h;
        }
        short* dst = (short*)wtb + ((size_t)m * 64 + d) * DIN + k0 + kc;
        *(short8*)dst       = *(short8*)&tmp[0];
        *(short8*)(dst + 8) = *(short8*)&tmp[8];
    }
}

// ---------------- Kernel 1: m-split MFMA projections ----------------
// 256 blocks x 384 threads (6 waves). Block: rows rowBase..rowBase+31.
// Wave w: matrix m = w>>1, row-half rh = w&1 (16 rows). No cross-wave reduction.
#define PP 72

__global__ __launch_bounds__(384) void proj_kernel(
    const float* __restrict__ x,
    const __hip_bfloat16* __restrict__ wtb,
    __hip_bfloat16* __restrict__ qb, __hip_bfloat16* __restrict__ kb,
    __hip_bfloat16* __restrict__ vt)
{
    __shared__ short xb[32][PP];        // x tile [row][k] (bf16)
    __shared__ short wb[3][64][PP];     // W^T tiles [m][col(d)][k]

    const int rowBase = blockIdx.x * 32;
    const int tid = threadIdx.x;
    const int lane = tid & 63;
    const int w = tid >> 6;             // 0..5
    const int m = w >> 1;               // matrix
    const int rh = w & 1;               // row half
    const int lo = lane & 15, hi = lane >> 4;

    f32x4 acc[4];
    #pragma unroll
    for (int cf = 0; cf < 4; ++cf) acc[cf] = (f32x4){0.f, 0.f, 0.f, 0.f};

    for (int kk = 0; kk < DIN; kk += 64) {
        // stage x 32x64 -> bf16 (first 256 threads, 8 f32 each)
        if (tid < 256) {
            const int r = tid >> 3;
            const int c0 = (tid & 7) * 8;
            float xa[8];
            *(float4*)&xa[0] = *(const float4*)(x + (size_t)(rowBase + r) * DIN + kk + c0);
            *(float4*)&xa[4] = *(const float4*)(x + (size_t)(rowBase + r) * DIN + kk + c0 + 4);
            *(short8*)&xb[r][c0] = cvt8(xa);
        }
        // stage W^T 3x64x64 (all 384 threads, 32 shorts each)
        {
            const int mm = tid / 128;
            const int rem = tid & 127;
            const int d = rem >> 1;
            const int kc = (rem & 1) * 32;
            const short* src = (const short*)wtb + ((size_t)mm * 64 + d) * DIN + kk + kc;
            short* dst = &wb[mm][d][kc];
            *(short8*)(dst + 0)  = *(const short8*)(src + 0);
            *(short8*)(dst + 8)  = *(const short8*)(src + 8);
            *(short8*)(dst + 16) = *(const short8*)(src + 16);
            *(short8*)(dst + 24) = *(const short8*)(src + 24);
        }
        __syncthreads();

        short8 a0 = *(short8*)&xb[rh * 16 + lo][hi * 8];
        short8 a1 = *(short8*)&xb[rh * 16 + lo][32 + hi * 8];
        #pragma unroll
        for (int cf = 0; cf < 4; ++cf) {
            short8 b0 = *(short8*)&wb[m][cf * 16 + lo][hi * 8];
            short8 b1 = *(short8*)&wb[m][cf * 16 + lo][32 + hi * 8];
            acc[cf] = __builtin_amdgcn_mfma_f32_16x16x32_bf16(a0, b0, acc[cf], 0, 0, 0);
            acc[cf] = __builtin_amdgcn_mfma_f32_16x16x32_bf16(a1, b1, acc[cf], 0, 0, 0);
        }
        __syncthreads();
    }

    // epilogue: C row = t (hi*4+r), col = d (cf*16+lo)
    if (m < 2) {
        __hip_bfloat16* o = (m == 0) ? qb : kb;
        #pragma unroll
        for (int cf = 0; cf < 4; ++cf)
            #pragma unroll
            for (int r = 0; r < 4; ++r)
                o[(size_t)(rowBase + rh * 16 + hi * 4 + r) * DQK + cf * 16 + lo] =
                    __float2bfloat16(acc[cf][r]);
    } else {
        #pragma unroll
        for (int cf = 0; cf < 4; ++cf)
            #pragma unroll
            for (int r = 0; r < 4; ++r)
                vt[(size_t)(cf * 16 + lo) * TT + rowBase + rh * 16 + hi * 4 + r] =
                    __float2bfloat16(acc[cf][r]);
    }
}

// ---------------- Kernel 2: MFMA triangular core (R4 champion, verbatim) ----------------
#define TM 128       // t rows per block (8 waves x 16)
#define TS 64        // s per step
#define SCHUNK 256   // s range per block (grid.y)
#define LP 72        // padded LDS row stride in shorts (144 B)

__global__ __launch_bounds__(512) void attn_kernel(
    const __hip_bfloat16* __restrict__ qb,
    const __hip_bfloat16* __restrict__ kb,
    const __hip_bfloat16* __restrict__ vt,
    const float* __restrict__ l,
    float* __restrict__ out)
{
    __shared__ short K_lds[TS][LP];      // K[s][k]
    __shared__ short V_lds[DQK][LP];     // Vt[d][s_local]
    __shared__ short S_lds[8][16][LP];   // per-wave (wave-private) S[t_loc][s_local]

    const int t0 = blockIdx.x * TM;
    const int sStart = blockIdx.y * SCHUNK;
    if (sStart >= t0 + TM) return;
    const int sEnd = min(sStart + SCHUNK, t0 + TM);

    const int tid = threadIdx.x;
    const int lane = tid & 63;
    const int w = tid >> 6;
    const int lo = lane & 15, hi = lane >> 4;
    const int trow = t0 + w * 16;
    const int r0 = hi * 4;
    const bool waveActive = (sStart <= trow + 15);

    short8 qf0, qf1;
    {
        const short* qp = (const short*)qb + (size_t)(trow + lo) * DQK;
        qf0 = *(const short8*)(qp + hi * 8);
        qf1 = *(const short8*)(qp + 32 + hi * 8);
    }

    f32x4 acc_o[4];
    #pragma unroll
    for (int i = 0; i < 4; ++i) acc_o[i] = (f32x4){0.f, 0.f, 0.f, 0.f};

    // l register double-buffer
    float lvC[4][4];
    float lvN[4][4];
    if (waveActive) {
        #pragma unroll
        for (int sub = 0; sub < 4; ++sub) {
            const int s_glob = sStart + sub * 16 + lo;
            #pragma unroll
            for (int r = 0; r < 4; ++r) {
                const int tg = trow + r0 + r;
                lvC[sub][r] = (s_glob <= tg)
                    ? __builtin_nontemporal_load(&l[(size_t)tg * TT + s_glob]) : 0.f;
            }
        }
    }

    for (int s0 = sStart; s0 < sEnd; s0 += TS) {
        // stage K (64x64) and Vt (64x64): one short8 per thread per matrix
        {
            const int row = tid >> 3;
            const int c8 = (tid & 7) * 8;
            *(short8*)&K_lds[row][c8] =
                *(const short8*)((const short*)kb + (size_t)(s0 + row) * DQK + c8);
            *(short8*)&V_lds[row][c8] =
                *(const short8*)((const short*)vt + (size_t)row * TT + s0 + c8);
        }
        __syncthreads();

        const bool active = (s0 <= trow + 15);
        const int sN = s0 + TS;
        const bool act_next = (sN < sEnd) && (sN <= trow + 15);

        // prefetch next step's l slice (flies during MFMA phase)
        if (act_next) {
            if (sN + 63 <= trow) {
                #pragma unroll
                for (int sub = 0; sub < 4; ++sub) {
                    const int s_glob = sN + sub * 16 + lo;
                    #pragma unroll
                    for (int r = 0; r < 4; ++r)
                        lvN[sub][r] = __builtin_nontemporal_load(
                            &l[(size_t)(trow + r0 + r) * TT + s_glob]);
                }
            } else {
                #pragma unroll
                for (int sub = 0; sub < 4; ++sub) {
                    const int s_glob = sN + sub * 16 + lo;
                    #pragma unroll
                    for (int r = 0; r < 4; ++r) {
                        const int tg = trow + r0 + r;
                        lvN[sub][r] = (s_glob <= tg)
                            ? __builtin_nontemporal_load(&l[(size_t)tg * TT + s_glob]) : 0.f;
                    }
                }
            }
        }

        if (active) {
            // QK^T -> *l -> bf16 -> S_lds (wave-private; lgkmcnt only, no barrier)
            #pragma unroll
            for (int sub = 0; sub < 4; ++sub) {
                f32x4 acc = (f32x4){0.f, 0.f, 0.f, 0.f};
                short8 b0 = *(short8*)&K_lds[sub * 16 + lo][hi * 8];
                short8 b1 = *(short8*)&K_lds[sub * 16 + lo][32 + hi * 8];
                acc = __builtin_amdgcn_mfma_f32_16x16x32_bf16(qf0, b0, acc, 0, 0, 0);
                acc = __builtin_amdgcn_mfma_f32_16x16x32_bf16(qf1, b1, acc, 0, 0, 0);
                #pragma unroll
                for (int r = 0; r < 4; ++r) {
                    float sv = acc[r] * lvC[sub][r];
                    __hip_bfloat16 h = __float2bfloat16(sv);
                    S_lds[w][r0 + r][sub * 16 + lo] = *(short*)&h;
                }
            }
            // PV
            short8 a0 = *(short8*)&S_lds[w][lo][hi * 8];
            short8 a1 = *(short8*)&S_lds[w][lo][32 + hi * 8];
            #pragma unroll
            for (int ds = 0; ds < 4; ++ds) {
                short8 b0 = *(short8*)&V_lds[ds * 16 + lo][hi * 8];
                short8 b1 = *(short8*)&V_lds[ds * 16 + lo][32 + hi * 8];
                acc_o[ds] = __builtin_amdgcn_mfma_f32_16x16x32_bf16(a0, b0, acc_o[ds], 0, 0, 0);
                acc_o[ds] = __builtin_amdgcn_mfma_f32_16x16x32_bf16(a1, b1, acc_o[ds], 0, 0, 0);
            }
        }
        __syncthreads();

        #pragma unroll
        for (int sub = 0; sub < 4; ++sub)
            #pragma unroll
            for (int r = 0; r < 4; ++r)
                lvC[sub][r] = lvN[sub][r];
    }

    if (waveActive) {
        #pragma unroll
        for (int ds = 0; ds < 4; ++ds) {
            #pragma unroll
            for (int r = 0; r < 4; ++r) {
                const int tg = trow + r0 + r;
                atomicAdd(&out[(size_t)tg * DQK + ds * 16 + lo], acc_o[ds][r]);
            }
        }
    }
}

extern "C" void kernel_launch(void* const* d_in, const int* in_sizes, int n_in,
                              void* d_out, int out_size, void* d_ws, size_t ws_size,
                              hipStream_t stream) {
    const float* x  = (const float*)d_in[0];
    const float* Wq = (const float*)d_in[1];
    const float* Wk = (const float*)d_in[2];
    const float* Wv = (const float*)d_in[3];
    const float* l  = (const float*)d_in[4];
    float* out = (float*)d_out;

    __hip_bfloat16* qb  = (__hip_bfloat16*)d_ws;
    __hip_bfloat16* kb  = qb + (size_t)TT * DQK;
    __hip_bfloat16* vt  = kb + (size_t)TT * DQK;
    __hip_bfloat16* wtb = vt + (size_t)TT * DQK;   // [3][64][512]

    init_kernel<<<48, 256, 0, stream>>>(Wq, Wk, Wv, wtb, out, out_size / 4);
    proj_kernel<<<TT / 32, 384, 0, stream>>>(x, wtb, qb, kb, vt);
    attn_kernel<<<dim3(TT / TM, TT / SCHUNK), 512, 0, stream>>>(qb, kb, vt, l, out);
}